// Round 3
// baseline (425.859 us; speedup 1.0000x reference)
//
#include <hip/hip_runtime.h>
#include <hip/hip_bf16.h>
#include <cstdint>

#define TT 300
#define NB 8

static constexpr float D_SR  = 0.90483741803595957f;   // exp(-1/10)
static constexpr float B_SR  = 0.27182818284590454f;   // e/10
static constexpr float D_RF  = 0.36787944117144233f;   // exp(-1)
static constexpr float A_RF  = -54.365636569180902f;   // -2*theta*e
static constexpr float THETA_F = 10.0f;
static constexpr float PGAIN = 11.0f;                  // 1.1*theta

typedef const float __attribute__((address_space(4)))* cfp;  // constant AS -> s_load

// ---- merged: psp+transpose on input (blocks 0..28) and weight transpose (29..)
__global__ void k_pre(const float* __restrict__ x, float* __restrict__ A,
                      const float* __restrict__ w1, const float* __restrict__ w2,
                      const float* __restrict__ w3, float* __restrict__ t1,
                      float* __restrict__ t2, float* __restrict__ t3) {
    if (blockIdx.x < 29) {
        const int NS = 7200;
        int i = blockIdx.x * 256 + threadIdx.x;
        if (i >= NS) return;
        const float4* x4 = (const float4*)(x + (size_t)i * TT);
        constexpr int G4 = 5, NG = TT / (4 * G4);
        float4 Aa[G4], Bb[G4];
        #pragma unroll
        for (int u = 0; u < G4; ++u) Aa[u] = x4[u];
        float p = 0.f, q = 0.f;
        for (int g = 0; g < NG; ++g) {
            if (g + 1 < NG) {
                #pragma unroll
                for (int u = 0; u < G4; ++u) Bb[u] = x4[(g + 1) * G4 + u];
            }
            int t0 = g * G4 * 4;
            #pragma unroll
            for (int u = 0; u < G4; ++u) {
                float xs[4] = {Aa[u].x, Aa[u].y, Aa[u].z, Aa[u].w};
                #pragma unroll
                for (int e = 0; e < 4; ++e) {
                    q = D_SR * (q + p);
                    p = D_SR * p + xs[e];
                    A[(size_t)(t0 + u * 4 + e) * NS + i] = B_SR * q;
                }
            }
            #pragma unroll
            for (int u = 0; u < G4; ++u) Aa[u] = Bb[u];
        }
    } else {
        int g = (blockIdx.x - 29) * 256 + threadIdx.x;
        if (g < 400) {                       // conv1: 16 oc x 25
            int oc = g / 25, s = g % 25;
            t1[s * 16 + oc] = w1[g];
        } else if (g < 400 + 4608) {         // conv2: 32 oc x 144
            int h = g - 400, oc = h / 144, s = h % 144;
            t2[s * 32 + oc] = w2[h];
        } else if (g < 400 + 4608 + 18432) { // conv3: 64 oc x 288
            int h = g - 5008, oc = h / 288, s = h % 288;
            t3[s * 64 + oc] = w3[h];
        }
    }
}

// ---- tiled conv: one WG per (t,n); LDS-padded input; SGPR (s_load) weights
template<int CI, int CO, int KS, int HI, int WI, int HO, int WO, int OCW, int J>
__global__ __launch_bounds__(256) void k_conv(const float* __restrict__ in,
                                              const float* __restrict__ wT,
                                              float* __restrict__ out) {
    constexpr int PW = WI + 2, PH = HI + 2, PST = PH * PW;
    __shared__ float lds[CI * PST];
    const int tid = threadIdx.x;
    const int tn  = blockIdx.x;
    cfp wc = (cfp)(uintptr_t)wT;
    const float* img = in + (size_t)tn * (CI * HI * WI);
    for (int idx = tid; idx < CI * PST; idx += 256) lds[idx] = 0.f;
    __syncthreads();
    for (int idx = tid; idx < CI * HI * WI; idx += 256) {
        int ic = idx / (HI * WI), rem = idx % (HI * WI);
        int r = rem / WI, c = rem % WI;
        lds[ic * PST + (r + 1) * PW + (c + 1)] = img[idx];
    }
    __syncthreads();

    const int wave = __builtin_amdgcn_readfirstlane(tid >> 6);
    const int lane = tid & 63;
    const int l = lane < 49 ? lane : 48;
    const int oc0 = (CO == OCW) ? 0 : wave * OCW;

    int pbase[J];
    #pragma unroll
    for (int j = 0; j < J; ++j) {
        int g = (CO == OCW) ? (wave * J + j) : j;
        int px = g * 49 + l;
        pbase[j] = (px / WO) * PW + (px % WO);
    }
    float acc[J * OCW];
    #pragma unroll
    for (int a = 0; a < J * OCW; ++a) acc[a] = 0.f;

    for (int ic = 0; ic < CI; ++ic) {
        #pragma unroll
        for (int kh = 0; kh < KS; ++kh) {
            #pragma unroll
            for (int kw = 0; kw < KS; ++kw) {
                const int step = (ic * KS + kh) * KS + kw;
                float iv[J];
                #pragma unroll
                for (int j = 0; j < J; ++j)
                    iv[j] = lds[ic * PST + pbase[j] + kh * PW + kw];
                #pragma unroll
                for (int o = 0; o < OCW; ++o) {
                    float wv = wc[(size_t)step * CO + oc0 + o];  // uniform -> SGPR
                    #pragma unroll
                    for (int j = 0; j < J; ++j) acc[j * OCW + o] += iv[j] * wv;
                }
            }
        }
    }
    if (lane < 49) {
        #pragma unroll
        for (int j = 0; j < J; ++j) {
            int g = (CO == OCW) ? (wave * J + j) : j;
            int px = g * 49 + lane;
            #pragma unroll
            for (int o = 0; o < OCW; ++o)
                out[((size_t)tn * CO + oc0 + o) * (HO * WO) + px] = acc[j * OCW + o];
        }
    }
}

// ---- fused spike(x4)->pool->psp->spike->psp; 4 lanes per pooled neuron
template<int C, int HI, int WI>
__global__ void k_fuse_pool(const float* __restrict__ U, float* __restrict__ X) {
    constexpr int HO = HI / 2, WO = WI / 2;
    constexpr int M   = NB * C * HO * WO;
    constexpr int NSI = NB * C * HI * WI;
    int gth = blockIdx.x * blockDim.x + threadIdx.x;
    int i = gth >> 2, sub = gth & 3;
    if (i >= M) return;
    int j = i % WO, r = (i / WO) % HO, nc = i / (WO * HO);
    const float* col = U + (size_t)(nc * HI + 2 * r + (sub >> 1)) * WI + 2 * j + (sub & 1);
    constexpr int G = 10, NG = TT / G;
    float Aa[G], Bb[G];
    #pragma unroll
    for (int u = 0; u < G; ++u) Aa[u] = col[(size_t)u * NSI];
    float p = 0, q = 0;                 // own sub-column spike state
    float P = 0, Q = 0, sp = 0, sq = 0, P2 = 0, Q2 = 0;  // pooled chain (redundant x4)
    for (int g = 0; g < NG; ++g) {
        if (g + 1 < NG) {
            #pragma unroll
            for (int u = 0; u < G; ++u) Bb[u] = col[(size_t)((g + 1) * G + u) * NSI];
        }
        #pragma unroll
        for (int u = 0; u < G; ++u) {
            int t = g * G + u;
            q = D_RF * (q + p);
            float v = Aa[u] + A_RF * q;
            float s = (v >= THETA_F) ? 1.f : 0.f;
            p = D_RF * p + s;
            float ss = s + __shfl_xor(s, 1);
            ss = ss + __shfl_xor(ss, 2);           // exact: small ints
            float xv = ss * PGAIN;
            Q = D_SR * (Q + P); P = D_SR * P + xv; float drive = B_SR * Q;
            sq = D_RF * (sq + sp);
            float v2 = drive + A_RF * sq;
            float sv = (v2 >= THETA_F) ? 1.f : 0.f;
            sp = D_RF * sp + sv;
            Q2 = D_SR * (Q2 + P2); P2 = D_SR * P2 + sv;
            if (sub == 0) X[(size_t)t * M + i] = B_SR * Q2;
        }
        #pragma unroll
        for (int u = 0; u < G; ++u) Aa[u] = Bb[u];
    }
}

// ---- fused spike -> psp, out-of-place, prefetched
__global__ void k_spike_psp(const float* __restrict__ U, float* __restrict__ X, int NS) {
    int i = blockIdx.x * blockDim.x + threadIdx.x;
    if (i >= NS) return;
    constexpr int G = 20, NG = TT / G;
    float Aa[G], Bb[G];
    #pragma unroll
    for (int u = 0; u < G; ++u) Aa[u] = U[(size_t)u * NS + i];
    float p = 0, q = 0, P = 0, Q = 0;
    for (int g = 0; g < NG; ++g) {
        if (g + 1 < NG) {
            #pragma unroll
            for (int u = 0; u < G; ++u) Bb[u] = U[(size_t)((g + 1) * G + u) * NS + i];
        }
        #pragma unroll
        for (int u = 0; u < G; ++u) {
            int t = g * G + u;
            q = D_RF * (q + p);
            float v = Aa[u] + A_RF * q;
            float s = (v >= THETA_F) ? 1.f : 0.f;
            p = D_RF * p + s;
            Q = D_SR * (Q + P); P = D_SR * P + s;
            X[(size_t)t * NS + i] = B_SR * Q;
        }
        #pragma unroll
        for (int u = 0; u < G; ++u) Aa[u] = Bb[u];
    }
}

// ---- dense: one wave per (t,n); coalesced loads + shuffle reduce
__global__ void k_dense(const float* __restrict__ X, const float* __restrict__ wf,
                        float* __restrict__ G_) {
    int tn = blockIdx.x;
    int lane = threadIdx.x;
    const float* xb = X + (size_t)tn * 3136;
    float acc[10];
    #pragma unroll
    for (int o = 0; o < 10; ++o) acc[o] = 0.f;
    for (int it = 0; it < 49; ++it) {
        int k = it * 64 + lane;
        float xv = xb[k];
        #pragma unroll
        for (int o = 0; o < 10; ++o) acc[o] += xv * wf[o * 3136 + k];
    }
    #pragma unroll
    for (int off = 32; off > 0; off >>= 1) {
        #pragma unroll
        for (int o = 0; o < 10; ++o) acc[o] += __shfl_down(acc[o], off);
    }
    if (lane == 0) {
        #pragma unroll
        for (int o = 0; o < 10; ++o) G_[tn * 10 + o] = acc[o];
    }
}

// ---- final spike on [T][80] -> out [N][10][T]
__global__ void k_spike_out(const float* __restrict__ G_, float* __restrict__ out) {
    int i = threadIdx.x;
    if (i >= 80) return;
    constexpr int G = 20, NG = TT / G;
    float Aa[G], Bb[G];
    #pragma unroll
    for (int u = 0; u < G; ++u) Aa[u] = G_[u * 80 + i];
    float p = 0, q = 0;
    for (int g = 0; g < NG; ++g) {
        if (g + 1 < NG) {
            #pragma unroll
            for (int u = 0; u < G; ++u) Bb[u] = G_[((g + 1) * G + u) * 80 + i];
        }
        #pragma unroll
        for (int u = 0; u < G; ++u) {
            int t = g * G + u;
            q = D_RF * (q + p);
            float v = Aa[u] + A_RF * q;
            float s = (v >= THETA_F) ? 1.f : 0.f;
            p = D_RF * p + s;
            out[(size_t)i * TT + t] = s;
        }
        #pragma unroll
        for (int u = 0; u < G; ++u) Aa[u] = Bb[u];
    }
}

static inline int cdiv(int a, int b) { return (a + b - 1) / b; }

extern "C" void kernel_launch(void* const* d_in, const int* in_sizes, int n_in,
                              void* d_out, int out_size, void* d_ws, size_t ws_size,
                              hipStream_t stream) {
    const float* x  = (const float*)d_in[0];   // [8,1,30,30,300]
    const float* w1 = (const float*)d_in[1];   // [16,1,5,5]
    const float* w2 = (const float*)d_in[2];   // [32,16,3,3]
    const float* w3 = (const float*)d_in[3];   // [64,32,3,3]
    const float* wf = (const float*)d_in[4];   // [10,64,7,7]
    float* out = (float*)d_out;                // [8,10,300]
    float* ws  = (float*)d_ws;

    // workspace (floats)
    float* A   = ws;                    // [300][7200]
    float* U1  = ws + 2160000;          // [300][100352] conv1 out (120 MB slot)
    float* X2  = ws + 32265600;         // [300][25088]
    float* Gg  = ws + 39792000;         // [300][80]
    float* wT1 = ws + 39816000;         // [25][16]
    float* wT2 = ws + 39816400;         // [144][32]
    float* wT3 = ws + 39821008;         // [288][64]
    // lifetime-disjoint aliases
    float* U2  = U1;                    // [300][50176]
    float* X4  = U1 + 16000000;         // [300][12544]
    float* U3  = X2;                    // [300][25088]
    float* X5  = U1;                    // [300][25088]

    const int B = 256;
    k_pre<<<29 + cdiv(23440, B), B, 0, stream>>>(x, A, w1, w2, w3, wT1, wT2, wT3);
    // conv1: 1->16, 5x5 pad1, 30x30 -> 28x28
    k_conv<1, 16, 5, 30, 30, 28, 28, 16, 4><<<2400, B, 0, stream>>>(A, wT1, U1);
    k_fuse_pool<16, 28, 28><<<cdiv(4 * 25088, B), B, 0, stream>>>(U1, X2);
    // conv2: 16->32, 3x3 pad1, 14x14
    k_conv<16, 32, 3, 14, 14, 14, 14, 32, 1><<<2400, B, 0, stream>>>(X2, wT2, U2);
    k_fuse_pool<32, 14, 14><<<cdiv(4 * 12544, B), B, 0, stream>>>(U2, X4);
    // conv3: 32->64, 3x3 pad1, 7x7
    k_conv<32, 64, 3, 7, 7, 7, 7, 16, 1><<<2400, B, 0, stream>>>(X4, wT3, U3);
    k_spike_psp<<<cdiv(25088, B), B, 0, stream>>>(U3, X5, 25088);
    k_dense<<<2400, 64, 0, stream>>>(X5, wf, Gg);
    k_spike_out<<<1, 128, 0, stream>>>(Gg, out);
}

// Round 4
// 385.565 us; speedup vs baseline: 1.1045x; 1.1045x over previous
//
#include <hip/hip_runtime.h>
#include <hip/hip_bf16.h>
#include <cstdint>

#define TT 300
#define NB 8

static constexpr float D_SR  = 0.90483741803595957f;   // exp(-1/10)
static constexpr float B_SR  = 0.27182818284590454f;   // e/10
static constexpr float D_RF  = 0.36787944117144233f;   // exp(-1)
static constexpr float A_RF  = -54.365636569180902f;   // -2*theta*e
static constexpr float THETA_F = 10.0f;
static constexpr float PGAIN = 11.0f;                  // 1.1*theta

typedef const float __attribute__((address_space(4)))* cfp;  // constant AS -> s_load

// ---- weight transpose: [oc][s] -> [s][oc]
__global__ void k_wtr(const float* __restrict__ w1, const float* __restrict__ w2,
                      const float* __restrict__ w3, float* __restrict__ t1,
                      float* __restrict__ t2, float* __restrict__ t3) {
    int g = blockIdx.x * blockDim.x + threadIdx.x;
    if (g < 400) {                       // conv1: 16 oc x 25
        int oc = g / 25, s = g % 25;
        t1[s * 16 + oc] = w1[g];
    } else if (g < 400 + 4608) {         // conv2: 32 oc x 144
        int h = g - 400, oc = h / 144, s = h % 144;
        t2[s * 32 + oc] = w2[h];
    } else if (g < 400 + 4608 + 18432) { // conv3: 64 oc x 288
        int h = g - 5008, oc = h / 288, s = h % 288;
        t3[s * 64 + oc] = w3[h];
    }
}

// ---- psp on input + transpose  in:[NS][T] -> out:[T][NS]
__global__ void k_psp_tr(const float* __restrict__ in, float* __restrict__ out, int NS) {
    int i = blockIdx.x * blockDim.x + threadIdx.x;
    if (i >= NS) return;
    const float4* x4 = (const float4*)(in + (size_t)i * TT);
    constexpr int G4 = 5, NG = TT / (4 * G4);
    float4 Aa[G4], Bb[G4];
    #pragma unroll
    for (int u = 0; u < G4; ++u) Aa[u] = x4[u];
    float p = 0.f, q = 0.f;
    for (int g = 0; g < NG; ++g) {
        if (g + 1 < NG) {
            #pragma unroll
            for (int u = 0; u < G4; ++u) Bb[u] = x4[(g + 1) * G4 + u];
        }
        int t0 = g * G4 * 4;
        #pragma unroll
        for (int u = 0; u < G4; ++u) {
            float xs[4] = {Aa[u].x, Aa[u].y, Aa[u].z, Aa[u].w};
            #pragma unroll
            for (int e = 0; e < 4; ++e) {
                q = D_SR * (q + p);
                p = D_SR * p + xs[e];
                out[(size_t)(t0 + u * 4 + e) * NS + i] = B_SR * q;
            }
        }
        #pragma unroll
        for (int u = 0; u < G4; ++u) Aa[u] = Bb[u];
    }
}

// ---- tiled conv (conv1/conv2): one WG per (t,n); LDS-padded input; scalar weights
template<int CI, int CO, int KS, int HI, int WI, int HO, int WO, int OCW, int J>
__global__ __launch_bounds__(256) void k_conv(const float* __restrict__ in,
                                              const float* __restrict__ wT,
                                              float* __restrict__ out) {
    constexpr int PW = WI + 2, PH = HI + 2, PST = PH * PW;
    __shared__ float lds[CI * PST];
    const int tid = threadIdx.x;
    const int tn  = blockIdx.x;
    cfp wc = (cfp)(uintptr_t)wT;
    const float* img = in + (size_t)tn * (CI * HI * WI);
    for (int idx = tid; idx < CI * PST; idx += 256) lds[idx] = 0.f;
    __syncthreads();
    for (int idx = tid; idx < CI * HI * WI; idx += 256) {
        int ic = idx / (HI * WI), rem = idx % (HI * WI);
        int r = rem / WI, c = rem % WI;
        lds[ic * PST + (r + 1) * PW + (c + 1)] = img[idx];
    }
    __syncthreads();

    const int wave = __builtin_amdgcn_readfirstlane(tid >> 6);
    const int lane = tid & 63;
    const int l = lane < 49 ? lane : 48;
    const int oc0 = (CO == OCW) ? 0 : wave * OCW;

    int pbase[J];
    #pragma unroll
    for (int j = 0; j < J; ++j) {
        int g = (CO == OCW) ? (wave * J + j) : j;
        int px = g * 49 + l;
        pbase[j] = (px / WO) * PW + (px % WO);
    }
    float acc[J * OCW];
    #pragma unroll
    for (int a = 0; a < J * OCW; ++a) acc[a] = 0.f;

    for (int ic = 0; ic < CI; ++ic) {
        #pragma unroll
        for (int kh = 0; kh < KS; ++kh) {
            #pragma unroll
            for (int kw = 0; kw < KS; ++kw) {
                const int step = (ic * KS + kh) * KS + kw;
                float iv[J];
                #pragma unroll
                for (int j = 0; j < J; ++j)
                    iv[j] = lds[ic * PST + pbase[j] + kh * PW + kw];
                #pragma unroll
                for (int o = 0; o < OCW; ++o) {
                    float wv = wc[(size_t)step * CO + oc0 + o];  // uniform -> SGPR
                    #pragma unroll
                    for (int j = 0; j < J; ++j) acc[j * OCW + o] += iv[j] * wv;
                }
            }
        }
    }
    if (lane < 49) {
        #pragma unroll
        for (int j = 0; j < J; ++j) {
            int g = (CO == OCW) ? (wave * J + j) : j;
            int px = g * 49 + lane;
            #pragma unroll
            for (int o = 0; o < OCW; ++o)
                out[((size_t)tn * CO + oc0 + o) * (HO * WO) + px] = acc[j * OCW + o];
        }
    }
}

// ---- conv3 (32->64, 3x3 pad1, 7x7): lane = oc; image in SGPRs; no LDS, no dead lanes
__global__ __launch_bounds__(256) void k_conv3(const float* __restrict__ in,
                                               const float* __restrict__ wT,
                                               float* __restrict__ out) {
    const int lane = threadIdx.x & 63;
    const int wave = __builtin_amdgcn_readfirstlane(threadIdx.x >> 6);
    const int tn   = blockIdx.x * 4 + wave;           // 600 blocks x 4 waves = 2400
    cfp img = (cfp)(uintptr_t)in + (size_t)tn * (32 * 49);
    const float* wp = wT + lane;                      // [step][64], lane-coalesced
    float acc[49];
    #pragma unroll
    for (int i = 0; i < 49; ++i) acc[i] = 0.f;
    for (int ic = 0; ic < 32; ++ic) {
        float w[9];
        #pragma unroll
        for (int s = 0; s < 9; ++s) w[s] = wp[(ic * 9 + s) * 64];
        float im[49];                                  // wave-uniform -> SGPRs
        #pragma unroll
        for (int k = 0; k < 49; ++k) im[k] = img[ic * 49 + k];
        #pragma unroll
        for (int kh = 0; kh < 3; ++kh) {
            #pragma unroll
            for (int kw = 0; kw < 3; ++kw) {
                #pragma unroll
                for (int r = 0; r < 7; ++r) {
                    const int ir = r + kh - 1;
                    if (ir < 0 || ir >= 7) continue;
                    #pragma unroll
                    for (int c = 0; c < 7; ++c) {
                        const int jc = c + kw - 1;
                        if (jc < 0 || jc >= 7) continue;
                        acc[r * 7 + c] += im[ir * 7 + jc] * w[kh * 3 + kw];
                    }
                }
            }
        }
    }
    #pragma unroll
    for (int px = 0; px < 49; ++px)
        out[((size_t)tn * 64 + lane) * 49 + px] = acc[px];
}

// ---- fused spike(x4)->pool->psp->spike->psp (round-2 form, 1 thread/pooled neuron)
template<int C, int HI, int WI>
__global__ void k_fuse_pool(const float* __restrict__ U, float* __restrict__ X) {
    constexpr int HO = HI / 2, WO = WI / 2;
    constexpr int M   = NB * C * HO * WO;
    constexpr int NSI = NB * C * HI * WI;
    int i = blockIdx.x * blockDim.x + threadIdx.x;
    if (i >= M) return;
    int j = i % WO, r = (i / WO) % HO, nc = i / (WO * HO);
    size_t base = (size_t)(nc * HI + 2 * r) * WI + 2 * j;
    const float2* R0 = (const float2*)(U + base);
    const float2* R1 = (const float2*)(U + base + WI);
    constexpr int G = 10, NG = TT / G;
    float2 A0[G], A1[G], B0[G], B1[G];
    #pragma unroll
    for (int u = 0; u < G; ++u) {
        A0[u] = R0[(size_t)u * (NSI / 2)];
        A1[u] = R1[(size_t)u * (NSI / 2)];
    }
    float p00=0,q00=0,p01=0,q01=0,p10=0,q10=0,p11=0,q11=0;
    float P=0,Q=0, sp=0,sq=0, P2=0,Q2=0;
    for (int g = 0; g < NG; ++g) {
        if (g + 1 < NG) {
            #pragma unroll
            for (int u = 0; u < G; ++u) {
                B0[u] = R0[(size_t)((g + 1) * G + u) * (NSI / 2)];
                B1[u] = R1[(size_t)((g + 1) * G + u) * (NSI / 2)];
            }
        }
        #pragma unroll
        for (int u = 0; u < G; ++u) {
            int t = g * G + u;
            float s0, s1, s2, s3;
            q00 = D_RF*(q00+p00); { float v = A0[u].x + A_RF*q00; s0 = (v>=THETA_F)?1.f:0.f; } p00 = D_RF*p00+s0;
            q01 = D_RF*(q01+p01); { float v = A0[u].y + A_RF*q01; s1 = (v>=THETA_F)?1.f:0.f; } p01 = D_RF*p01+s1;
            q10 = D_RF*(q10+p10); { float v = A1[u].x + A_RF*q10; s2 = (v>=THETA_F)?1.f:0.f; } p10 = D_RF*p10+s2;
            q11 = D_RF*(q11+p11); { float v = A1[u].y + A_RF*q11; s3 = (v>=THETA_F)?1.f:0.f; } p11 = D_RF*p11+s3;
            float x = (s0 + s1 + s2 + s3) * PGAIN;
            Q = D_SR*(Q+P); P = D_SR*P + x; float drive = B_SR*Q;
            sq = D_RF*(sq+sp); float v2 = drive + A_RF*sq; float sv = (v2>=THETA_F)?1.f:0.f; sp = D_RF*sp+sv;
            Q2 = D_SR*(Q2+P2); P2 = D_SR*P2 + sv;
            X[(size_t)t * M + i] = B_SR * Q2;
        }
        #pragma unroll
        for (int u = 0; u < G; ++u) { A0[u] = B0[u]; A1[u] = B1[u]; }
    }
}

// ---- fused spike -> psp, out-of-place, prefetched
__global__ void k_spike_psp(const float* __restrict__ U, float* __restrict__ X, int NS) {
    int i = blockIdx.x * blockDim.x + threadIdx.x;
    if (i >= NS) return;
    constexpr int G = 20, NG = TT / G;
    float Aa[G], Bb[G];
    #pragma unroll
    for (int u = 0; u < G; ++u) Aa[u] = U[(size_t)u * NS + i];
    float p = 0, q = 0, P = 0, Q = 0;
    for (int g = 0; g < NG; ++g) {
        if (g + 1 < NG) {
            #pragma unroll
            for (int u = 0; u < G; ++u) Bb[u] = U[(size_t)((g + 1) * G + u) * NS + i];
        }
        #pragma unroll
        for (int u = 0; u < G; ++u) {
            int t = g * G + u;
            q = D_RF * (q + p);
            float v = Aa[u] + A_RF * q;
            float s = (v >= THETA_F) ? 1.f : 0.f;
            p = D_RF * p + s;
            Q = D_SR * (Q + P); P = D_SR * P + s;
            X[(size_t)t * NS + i] = B_SR * Q;
        }
        #pragma unroll
        for (int u = 0; u < G; ++u) Aa[u] = Bb[u];
    }
}

// ---- dense: one wave per (t,n)
__global__ void k_dense(const float* __restrict__ X, const float* __restrict__ wf,
                        float* __restrict__ G_) {
    int tn = blockIdx.x;
    int lane = threadIdx.x;
    const float* xb = X + (size_t)tn * 3136;
    float acc[10];
    #pragma unroll
    for (int o = 0; o < 10; ++o) acc[o] = 0.f;
    for (int it = 0; it < 49; ++it) {
        int k = it * 64 + lane;
        float xv = xb[k];
        #pragma unroll
        for (int o = 0; o < 10; ++o) acc[o] += xv * wf[o * 3136 + k];
    }
    #pragma unroll
    for (int off = 32; off > 0; off >>= 1) {
        #pragma unroll
        for (int o = 0; o < 10; ++o) acc[o] += __shfl_down(acc[o], off);
    }
    if (lane == 0) {
        #pragma unroll
        for (int o = 0; o < 10; ++o) G_[tn * 10 + o] = acc[o];
    }
}

// ---- final spike on [T][80] -> out [N][10][T]
__global__ void k_spike_out(const float* __restrict__ G_, float* __restrict__ out) {
    int i = threadIdx.x;
    if (i >= 80) return;
    constexpr int G = 20, NG = TT / G;
    float Aa[G], Bb[G];
    #pragma unroll
    for (int u = 0; u < G; ++u) Aa[u] = G_[u * 80 + i];
    float p = 0, q = 0;
    for (int g = 0; g < NG; ++g) {
        if (g + 1 < NG) {
            #pragma unroll
            for (int u = 0; u < G; ++u) Bb[u] = G_[((g + 1) * G + u) * 80 + i];
        }
        #pragma unroll
        for (int u = 0; u < G; ++u) {
            int t = g * G + u;
            q = D_RF * (q + p);
            float v = Aa[u] + A_RF * q;
            float s = (v >= THETA_F) ? 1.f : 0.f;
            p = D_RF * p + s;
            out[(size_t)i * TT + t] = s;
        }
        #pragma unroll
        for (int u = 0; u < G; ++u) Aa[u] = Bb[u];
    }
}

static inline int cdiv(int a, int b) { return (a + b - 1) / b; }

extern "C" void kernel_launch(void* const* d_in, const int* in_sizes, int n_in,
                              void* d_out, int out_size, void* d_ws, size_t ws_size,
                              hipStream_t stream) {
    const float* x  = (const float*)d_in[0];   // [8,1,30,30,300]
    const float* w1 = (const float*)d_in[1];   // [16,1,5,5]
    const float* w2 = (const float*)d_in[2];   // [32,16,3,3]
    const float* w3 = (const float*)d_in[3];   // [64,32,3,3]
    const float* wf = (const float*)d_in[4];   // [10,64,7,7]
    float* out = (float*)d_out;                // [8,10,300]
    float* ws  = (float*)d_ws;

    // workspace (floats)
    float* A   = ws;                    // [300][7200]
    float* U1  = ws + 2160000;          // [300][100352] (120 MB slot)
    float* X2  = ws + 32265600;         // [300][25088]
    float* Gg  = ws + 39792000;         // [300][80]
    float* wT1 = ws + 39816000;         // [25][16]
    float* wT2 = ws + 39816400;         // [144][32]
    float* wT3 = ws + 39821008;         // [288][64]
    // lifetime-disjoint aliases
    float* U2  = U1;                    // [300][50176]
    float* X4  = U1 + 16000000;         // [300][12544]
    float* U3  = X2;                    // [300][25088]
    float* X5  = U1;                    // [300][25088]

    const int B = 256;
    k_wtr<<<cdiv(23440, B), B, 0, stream>>>(w1, w2, w3, wT1, wT2, wT3);
    k_psp_tr<<<cdiv(7200, B), B, 0, stream>>>(x, A, 7200);
    // conv1: 1->16, 5x5 pad1, 30x30 -> 28x28
    k_conv<1, 16, 5, 30, 30, 28, 28, 16, 4><<<2400, B, 0, stream>>>(A, wT1, U1);
    k_fuse_pool<16, 28, 28><<<cdiv(25088, B), B, 0, stream>>>(U1, X2);
    // conv2: 16->32, 3x3 pad1, 14x14
    k_conv<16, 32, 3, 14, 14, 14, 14, 32, 1><<<2400, B, 0, stream>>>(X2, wT2, U2);
    k_fuse_pool<32, 14, 14><<<cdiv(12544, B), B, 0, stream>>>(U2, X4);
    // conv3: 32->64, 3x3 pad1, 7x7 — SGPR-image scheme
    k_conv3<<<600, B, 0, stream>>>(X4, wT3, U3);
    k_spike_psp<<<cdiv(25088, B), B, 0, stream>>>(U3, X5, 25088);
    k_dense<<<2400, 64, 0, stream>>>(X5, wf, Gg);
    k_spike_out<<<1, 128, 0, stream>>>(Gg, out);
}

// Round 5
// 381.471 us; speedup vs baseline: 1.1164x; 1.0107x over previous
//
#include <hip/hip_runtime.h>
#include <hip/hip_bf16.h>
#include <cstdint>

#define TT 300
#define NB 8

static constexpr float D_SR  = 0.90483741803595957f;   // exp(-1/10)
static constexpr float B_SR  = 0.27182818284590454f;   // e/10
static constexpr float D_RF  = 0.36787944117144233f;   // exp(-1)
static constexpr float A_RF  = -54.365636569180902f;   // -2*theta*e
static constexpr float THETA_F = 10.0f;
static constexpr float PGAIN = 11.0f;                  // 1.1*theta

typedef const float __attribute__((address_space(4)))* cfp;  // constant AS -> s_load

// ---- weight transpose: [oc][s] -> [s][oc]
__global__ void k_wtr(const float* __restrict__ w1, const float* __restrict__ w2,
                      const float* __restrict__ w3, float* __restrict__ t1,
                      float* __restrict__ t2, float* __restrict__ t3) {
    int g = blockIdx.x * blockDim.x + threadIdx.x;
    if (g < 400) {                       // conv1: 16 oc x 25
        int oc = g / 25, s = g % 25;
        t1[s * 16 + oc] = w1[g];
    } else if (g < 400 + 4608) {         // conv2: 32 oc x 144
        int h = g - 400, oc = h / 144, s = h % 144;
        t2[s * 32 + oc] = w2[h];
    } else if (g < 400 + 4608 + 18432) { // conv3: 64 oc x 288
        int h = g - 5008, oc = h / 288, s = h % 288;
        t3[s * 64 + oc] = w3[h];
    }
}

// ---- psp on input + transpose  in:[NS][T] -> out:[T][NS]
__global__ void k_psp_tr(const float* __restrict__ in, float* __restrict__ out, int NS) {
    int i = blockIdx.x * blockDim.x + threadIdx.x;
    if (i >= NS) return;
    const float4* x4 = (const float4*)(in + (size_t)i * TT);
    constexpr int G4 = 5, NG = TT / (4 * G4);
    float4 Aa[G4], Bb[G4];
    #pragma unroll
    for (int u = 0; u < G4; ++u) Aa[u] = x4[u];
    float p = 0.f, q = 0.f;
    for (int g = 0; g < NG; ++g) {
        if (g + 1 < NG) {
            #pragma unroll
            for (int u = 0; u < G4; ++u) Bb[u] = x4[(g + 1) * G4 + u];
        }
        int t0 = g * G4 * 4;
        #pragma unroll
        for (int u = 0; u < G4; ++u) {
            float xs[4] = {Aa[u].x, Aa[u].y, Aa[u].z, Aa[u].w};
            #pragma unroll
            for (int e = 0; e < 4; ++e) {
                q = D_SR * (q + p);
                p = D_SR * p + xs[e];
                out[(size_t)(t0 + u * 4 + e) * NS + i] = B_SR * q;
            }
        }
        #pragma unroll
        for (int u = 0; u < G4; ++u) Aa[u] = Bb[u];
    }
}

// ---- tiled conv (conv1/conv2): one WG per (t,n); LDS-padded input; scalar weights
template<int CI, int CO, int KS, int HI, int WI, int HO, int WO, int OCW, int J>
__global__ __launch_bounds__(256) void k_conv(const float* __restrict__ in,
                                              const float* __restrict__ wT,
                                              float* __restrict__ out) {
    constexpr int PW = WI + 2, PH = HI + 2, PST = PH * PW;
    __shared__ float lds[CI * PST];
    const int tid = threadIdx.x;
    const int tn  = blockIdx.x;
    cfp wc = (cfp)(uintptr_t)wT;
    const float* img = in + (size_t)tn * (CI * HI * WI);
    for (int idx = tid; idx < CI * PST; idx += 256) lds[idx] = 0.f;
    __syncthreads();
    for (int idx = tid; idx < CI * HI * WI; idx += 256) {
        int ic = idx / (HI * WI), rem = idx % (HI * WI);
        int r = rem / WI, c = rem % WI;
        lds[ic * PST + (r + 1) * PW + (c + 1)] = img[idx];
    }
    __syncthreads();

    const int wave = __builtin_amdgcn_readfirstlane(tid >> 6);
    const int lane = tid & 63;
    const int l = lane < 49 ? lane : 48;
    const int oc0 = (CO == OCW) ? 0 : wave * OCW;

    int pbase[J];
    #pragma unroll
    for (int j = 0; j < J; ++j) {
        int g = (CO == OCW) ? (wave * J + j) : j;
        int px = g * 49 + l;
        pbase[j] = (px / WO) * PW + (px % WO);
    }
    float acc[J * OCW];
    #pragma unroll
    for (int a = 0; a < J * OCW; ++a) acc[a] = 0.f;

    for (int ic = 0; ic < CI; ++ic) {
        #pragma unroll
        for (int kh = 0; kh < KS; ++kh) {
            #pragma unroll
            for (int kw = 0; kw < KS; ++kw) {
                const int step = (ic * KS + kh) * KS + kw;
                float iv[J];
                #pragma unroll
                for (int j = 0; j < J; ++j)
                    iv[j] = lds[ic * PST + pbase[j] + kh * PW + kw];
                #pragma unroll
                for (int o = 0; o < OCW; ++o) {
                    float wv = wc[(size_t)step * CO + oc0 + o];  // uniform -> SGPR
                    #pragma unroll
                    for (int j = 0; j < J; ++j) acc[j * OCW + o] += iv[j] * wv;
                }
            }
        }
    }
    if (lane < 49) {
        #pragma unroll
        for (int j = 0; j < J; ++j) {
            int g = (CO == OCW) ? (wave * J + j) : j;
            int px = g * 49 + lane;
            #pragma unroll
            for (int o = 0; o < OCW; ++o)
                out[((size_t)tn * CO + oc0 + o) * (HO * WO) + px] = acc[j * OCW + o];
        }
    }
}

// ---- conv3 v2: lane=oc, image in LDS (broadcast ds_read), 2 waves split px rows.
// Per-acc accumulation order ic->kh->kw preserved (ir ascending => kh ascending).
template<int RB, int RE, int IRB, int IRE>
__device__ __forceinline__ void conv3_rows(const float* lds, const float* wp,
                                           float* __restrict__ out, int tn, int lane) {
    constexpr int NR = RE - RB;
    float acc[NR * 7];
    #pragma unroll
    for (int a = 0; a < NR * 7; ++a) acc[a] = 0.f;
    for (int ic = 0; ic < 32; ++ic) {
        float w[9];
        #pragma unroll
        for (int s = 0; s < 9; ++s) w[s] = wp[(ic * 9 + s) * 64];  // coalesced VMEM
        #pragma unroll
        for (int ir = IRB; ir < IRE; ++ir) {
            float row[7];
            #pragma unroll
            for (int c = 0; c < 7; ++c) row[c] = lds[ic * 49 + ir * 7 + c];  // broadcast
            #pragma unroll
            for (int kh = 0; kh < 3; ++kh) {
                const int r = ir + 1 - kh;
                if (r < RB || r >= RE) continue;
                #pragma unroll
                for (int c = 0; c < 7; ++c) {
                    #pragma unroll
                    for (int kw = 0; kw < 3; ++kw) {
                        const int jc = c + kw - 1;
                        if (jc < 0 || jc >= 7) continue;
                        acc[(r - RB) * 7 + c] += row[jc] * w[kh * 3 + kw];
                    }
                }
            }
        }
    }
    #pragma unroll
    for (int r = RB; r < RE; ++r)
        #pragma unroll
        for (int c = 0; c < 7; ++c)
            out[((size_t)tn * 64 + lane) * 49 + r * 7 + c] = acc[(r - RB) * 7 + c];
}

__global__ __launch_bounds__(128) void k_conv3(const float* __restrict__ in,
                                               const float* __restrict__ wT,
                                               float* __restrict__ out) {
    __shared__ float lds[1568];                        // one [32][7][7] image
    const int tid = threadIdx.x;
    const int tn  = blockIdx.x;
    const float4* src = (const float4*)(in + (size_t)tn * 1568);
    for (int idx = tid; idx < 392; idx += 128) ((float4*)lds)[idx] = src[idx];
    __syncthreads();
    const int lane = tid & 63;
    const float* wp = wT + lane;                       // [step][64]
    if (tid < 64) conv3_rows<0, 4, 0, 5>(lds, wp, out, tn, lane);  // px rows 0..3
    else          conv3_rows<4, 7, 3, 7>(lds, wp, out, tn, lane);  // px rows 4..6
}

// ---- fused spike(x4)->pool->psp->spike->psp (1 thread per pooled neuron)
template<int C, int HI, int WI>
__global__ void k_fuse_pool(const float* __restrict__ U, float* __restrict__ X) {
    constexpr int HO = HI / 2, WO = WI / 2;
    constexpr int M   = NB * C * HO * WO;
    constexpr int NSI = NB * C * HI * WI;
    int i = blockIdx.x * blockDim.x + threadIdx.x;
    if (i >= M) return;
    int j = i % WO, r = (i / WO) % HO, nc = i / (WO * HO);
    size_t base = (size_t)(nc * HI + 2 * r) * WI + 2 * j;
    const float2* R0 = (const float2*)(U + base);
    const float2* R1 = (const float2*)(U + base + WI);
    constexpr int G = 10, NG = TT / G;
    float2 A0[G], A1[G], B0[G], B1[G];
    #pragma unroll
    for (int u = 0; u < G; ++u) {
        A0[u] = R0[(size_t)u * (NSI / 2)];
        A1[u] = R1[(size_t)u * (NSI / 2)];
    }
    float p00=0,q00=0,p01=0,q01=0,p10=0,q10=0,p11=0,q11=0;
    float P=0,Q=0, sp=0,sq=0, P2=0,Q2=0;
    for (int g = 0; g < NG; ++g) {
        if (g + 1 < NG) {
            #pragma unroll
            for (int u = 0; u < G; ++u) {
                B0[u] = R0[(size_t)((g + 1) * G + u) * (NSI / 2)];
                B1[u] = R1[(size_t)((g + 1) * G + u) * (NSI / 2)];
            }
        }
        #pragma unroll
        for (int u = 0; u < G; ++u) {
            int t = g * G + u;
            float s0, s1, s2, s3;
            q00 = D_RF*(q00+p00); { float v = A0[u].x + A_RF*q00; s0 = (v>=THETA_F)?1.f:0.f; } p00 = D_RF*p00+s0;
            q01 = D_RF*(q01+p01); { float v = A0[u].y + A_RF*q01; s1 = (v>=THETA_F)?1.f:0.f; } p01 = D_RF*p01+s1;
            q10 = D_RF*(q10+p10); { float v = A1[u].x + A_RF*q10; s2 = (v>=THETA_F)?1.f:0.f; } p10 = D_RF*p10+s2;
            q11 = D_RF*(q11+p11); { float v = A1[u].y + A_RF*q11; s3 = (v>=THETA_F)?1.f:0.f; } p11 = D_RF*p11+s3;
            float x = (s0 + s1 + s2 + s3) * PGAIN;
            Q = D_SR*(Q+P); P = D_SR*P + x; float drive = B_SR*Q;
            sq = D_RF*(sq+sp); float v2 = drive + A_RF*sq; float sv = (v2>=THETA_F)?1.f:0.f; sp = D_RF*sp+sv;
            Q2 = D_SR*(Q2+P2); P2 = D_SR*P2 + sv;
            X[(size_t)t * M + i] = B_SR * Q2;
        }
        #pragma unroll
        for (int u = 0; u < G; ++u) { A0[u] = B0[u]; A1[u] = B1[u]; }
    }
}

// ---- fused spike -> psp, out-of-place, prefetched
__global__ void k_spike_psp(const float* __restrict__ U, float* __restrict__ X, int NS) {
    int i = blockIdx.x * blockDim.x + threadIdx.x;
    if (i >= NS) return;
    constexpr int G = 20, NG = TT / G;
    float Aa[G], Bb[G];
    #pragma unroll
    for (int u = 0; u < G; ++u) Aa[u] = U[(size_t)u * NS + i];
    float p = 0, q = 0, P = 0, Q = 0;
    for (int g = 0; g < NG; ++g) {
        if (g + 1 < NG) {
            #pragma unroll
            for (int u = 0; u < G; ++u) Bb[u] = U[(size_t)((g + 1) * G + u) * NS + i];
        }
        #pragma unroll
        for (int u = 0; u < G; ++u) {
            int t = g * G + u;
            q = D_RF * (q + p);
            float v = Aa[u] + A_RF * q;
            float s = (v >= THETA_F) ? 1.f : 0.f;
            p = D_RF * p + s;
            Q = D_SR * (Q + P); P = D_SR * P + s;
            X[(size_t)t * NS + i] = B_SR * Q;
        }
        #pragma unroll
        for (int u = 0; u < G; ++u) Aa[u] = Bb[u];
    }
}

// ---- dense: one wave per (t,n)
__global__ void k_dense(const float* __restrict__ X, const float* __restrict__ wf,
                        float* __restrict__ G_) {
    int tn = blockIdx.x;
    int lane = threadIdx.x;
    const float* xb = X + (size_t)tn * 3136;
    float acc[10];
    #pragma unroll
    for (int o = 0; o < 10; ++o) acc[o] = 0.f;
    for (int it = 0; it < 49; ++it) {
        int k = it * 64 + lane;
        float xv = xb[k];
        #pragma unroll
        for (int o = 0; o < 10; ++o) acc[o] += xv * wf[o * 3136 + k];
    }
    #pragma unroll
    for (int off = 32; off > 0; off >>= 1) {
        #pragma unroll
        for (int o = 0; o < 10; ++o) acc[o] += __shfl_down(acc[o], off);
    }
    if (lane == 0) {
        #pragma unroll
        for (int o = 0; o < 10; ++o) G_[tn * 10 + o] = acc[o];
    }
}

// ---- final spike on [T][80] -> out [N][10][T]
__global__ void k_spike_out(const float* __restrict__ G_, float* __restrict__ out) {
    int i = threadIdx.x;
    if (i >= 80) return;
    constexpr int G = 20, NG = TT / G;
    float Aa[G], Bb[G];
    #pragma unroll
    for (int u = 0; u < G; ++u) Aa[u] = G_[u * 80 + i];
    float p = 0, q = 0;
    for (int g = 0; g < NG; ++g) {
        if (g + 1 < NG) {
            #pragma unroll
            for (int u = 0; u < G; ++u) Bb[u] = G_[((g + 1) * G + u) * 80 + i];
        }
        #pragma unroll
        for (int u = 0; u < G; ++u) {
            int t = g * G + u;
            q = D_RF * (q + p);
            float v = Aa[u] + A_RF * q;
            float s = (v >= THETA_F) ? 1.f : 0.f;
            p = D_RF * p + s;
            out[(size_t)i * TT + t] = s;
        }
        #pragma unroll
        for (int u = 0; u < G; ++u) Aa[u] = Bb[u];
    }
}

static inline int cdiv(int a, int b) { return (a + b - 1) / b; }

extern "C" void kernel_launch(void* const* d_in, const int* in_sizes, int n_in,
                              void* d_out, int out_size, void* d_ws, size_t ws_size,
                              hipStream_t stream) {
    const float* x  = (const float*)d_in[0];   // [8,1,30,30,300]
    const float* w1 = (const float*)d_in[1];   // [16,1,5,5]
    const float* w2 = (const float*)d_in[2];   // [32,16,3,3]
    const float* w3 = (const float*)d_in[3];   // [64,32,3,3]
    const float* wf = (const float*)d_in[4];   // [10,64,7,7]
    float* out = (float*)d_out;                // [8,10,300]
    float* ws  = (float*)d_ws;

    // workspace (floats)
    float* A   = ws;                    // [300][7200]
    float* U1  = ws + 2160000;          // [300][100352] (120 MB slot)
    float* X2  = ws + 32265600;         // [300][25088]
    float* Gg  = ws + 39792000;         // [300][80]
    float* wT1 = ws + 39816000;         // [25][16]
    float* wT2 = ws + 39816400;         // [144][32]
    float* wT3 = ws + 39821008;         // [288][64]
    // lifetime-disjoint aliases
    float* U2  = U1;                    // [300][50176]
    float* X4  = U1 + 16000000;         // [300][12544]
    float* U3  = X2;                    // [300][25088]
    float* X5  = U1;                    // [300][25088]

    const int B = 256;
    k_wtr<<<cdiv(23440, B), B, 0, stream>>>(w1, w2, w3, wT1, wT2, wT3);
    k_psp_tr<<<cdiv(7200, B), B, 0, stream>>>(x, A, 7200);
    // conv1: 1->16, 5x5 pad1, 30x30 -> 28x28
    k_conv<1, 16, 5, 30, 30, 28, 28, 16, 4><<<2400, B, 0, stream>>>(A, wT1, U1);
    k_fuse_pool<16, 28, 28><<<cdiv(25088, B), B, 0, stream>>>(U1, X2);
    // conv2: 16->32, 3x3 pad1, 14x14
    k_conv<16, 32, 3, 14, 14, 14, 14, 32, 1><<<2400, B, 0, stream>>>(X2, wT2, U2);
    k_fuse_pool<32, 14, 14><<<cdiv(12544, B), B, 0, stream>>>(U2, X4);
    // conv3: 32->64, 3x3 pad1, 7x7 — LDS image, 2 waves split px rows
    k_conv3<<<2400, 128, 0, stream>>>(X4, wT3, U3);
    k_spike_psp<<<cdiv(25088, B), B, 0, stream>>>(U3, X5, 25088);
    k_dense<<<2400, 64, 0, stream>>>(X5, wf, Gg);
    k_spike_out<<<1, 128, 0, stream>>>(Gg, out);
}